// Round 4
// baseline (652.458 us; speedup 1.0000x reference)
//
#include <hip/hip_runtime.h>

#define THREADS 256
#define B_DIM   4
#define H_DIM   1024
#define L_DIM   4096
#define NFFT    4096      // half-length complex FFT size (real n = 8192)
#define PI_F     3.14159265358979323846f
#define TWO_PI_F 6.28318530717958647692f

__device__ __forceinline__ float2 cmulf(float2 a, float2 b) {
    return make_float2(a.x*b.x - a.y*b.y, a.x*b.y + a.y*b.x);
}
__device__ __forceinline__ float2 caddf(float2 a, float2 b){ return make_float2(a.x+b.x, a.y+b.y); }
__device__ __forceinline__ float2 csubf(float2 a, float2 b){ return make_float2(a.x-b.x, a.y-b.y); }

// XOR swizzle: bank-pair = d2^d1^d0 -> ~4 lanes/bank-pair (b64 floor) on all patterns
__device__ __forceinline__ int swz(int i) { return i ^ ((i>>4)&15) ^ ((i>>8)&15); }

// w[kk] = e^{i*base*kk}, kk=1..15, via 1 sincos + squaring tree (14 cmul)
__device__ __forceinline__ void make_tw(float base, float2 w[16]) {
    float sn, cs; __sincosf(base, &sn, &cs);
    w[1]  = make_float2(cs, sn);
    w[2]  = cmulf(w[1], w[1]);
    w[3]  = cmulf(w[2], w[1]);
    w[4]  = cmulf(w[2], w[2]);
    w[5]  = cmulf(w[4], w[1]);
    w[6]  = cmulf(w[4], w[2]);
    w[7]  = cmulf(w[4], w[3]);
    w[8]  = cmulf(w[4], w[4]);
    w[9]  = cmulf(w[8], w[1]);
    w[10] = cmulf(w[8], w[2]);
    w[11] = cmulf(w[8], w[3]);
    w[12] = cmulf(w[8], w[4]);
    w[13] = cmulf(w[8], w[5]);
    w[14] = cmulf(w[8], w[6]);
    w[15] = cmulf(w[8], w[7]);
}

// W16^q = e^{SGN*2pi*i*q/16}
__device__ __forceinline__ float2 w16c(int q, float s) {
    constexpr float C[8] = {1.f, 0.9238795325f, 0.7071067812f, 0.3826834324f,
                            0.f, -0.3826834324f, -0.7071067812f, -0.9238795325f};
    constexpr float S[8] = {0.f, 0.3826834324f, 0.7071067812f, 0.9238795325f,
                            1.f, 0.9238795325f, 0.7071067812f, 0.3826834324f};
    return make_float2(C[q], s*S[q]);
}

template<int SGN>
__device__ __forceinline__ float2 twq(float2 d, int q) {
    if (q == 0) return d;
    if (q == 4) return make_float2((float)(-SGN)*d.y, (float)SGN*d.x);
    return cmulf(d, w16c(q, (float)SGN));
}

// Radix-2 DIF 16-pt DFT: natural-order input, bit-reversed output (bin k at reg REV4[k]).
template<int SGN, bool HZ>
__device__ __forceinline__ void dif16(float2 v[16]) {
    if (HZ) {
        #pragma unroll
        for (int i = 0; i < 8; ++i) {
            float2 a = v[i];
            v[i+8] = twq<SGN>(a, i);
        }
    } else {
        #pragma unroll
        for (int i = 0; i < 8; ++i) {
            float2 a = v[i], b = v[i+8];
            v[i]   = caddf(a,b);
            v[i+8] = twq<SGN>(csubf(a,b), i);
        }
    }
    #pragma unroll
    for (int h = 4; h >= 1; h >>= 1) {
        const int step = 8 / h;
        #pragma unroll
        for (int g = 0; g < 16; g += 2*h) {
            #pragma unroll
            for (int i = 0; i < h; ++i) {
                float2 a = v[g+i], b = v[g+i+h];
                v[g+i]   = caddf(a,b);
                v[g+i+h] = twq<SGN>(csubf(a,b), i*step);
            }
        }
    }
}

// Radix-2 DIT 16-pt DFT: bit-reversed input, natural-order output.
// HALF: only outputs v[0..7] are needed (skip the subs of the final stage).
template<int SGN, bool HALF>
__device__ __forceinline__ void dit16(float2 v[16]) {
    #pragma unroll
    for (int h = 1; h <= 4; h <<= 1) {
        const int step = 8 / h;
        #pragma unroll
        for (int g = 0; g < 16; g += 2*h) {
            #pragma unroll
            for (int i = 0; i < h; ++i) {
                float2 a = v[g+i];
                float2 b = twq<SGN>(v[g+i+h], i*step);
                v[g+i]   = caddf(a,b);
                v[g+i+h] = csubf(a,b);
            }
        }
    }
    // final stage h=8
    #pragma unroll
    for (int i = 0; i < 8; ++i) {
        float2 a = v[i];
        float2 b = twq<SGN>(v[i+8], i);
        v[i] = caddf(a,b);
        if (!HALF) v[i+8] = csubf(a,b);
    }
}

// Forward 3-level radix-16 FFT of a zero-padded packed real row into LDS Z.
// On exit (no trailing barrier): position p holds bin drev(p), swizzled.
__device__ __forceinline__ void fwd_fft_row(const float2* __restrict__ src, float2* Z, int t) {
    constexpr int REV4[16] = {0,8,4,12,2,10,6,14,1,9,5,13,3,11,7,15};
    float2 v[16], w[16];
    #pragma unroll
    for (int r = 0; r < 8; ++r) v[r] = src[256*r + t];
    dif16<-1, true>(v);
    make_tw(-TWO_PI_F * (float)t / (float)NFFT, w);
    #pragma unroll
    for (int kk = 1; kk < 16; ++kk) v[REV4[kk]] = cmulf(v[REV4[kk]], w[kk]);
    #pragma unroll
    for (int kk = 0; kk < 16; ++kk) Z[swz(256*kk + t)] = v[REV4[kk]];
    __syncthreads();

    const int k1 = t >> 4, m = t & 15;
    const int rb = 256*k1 + m;
    #pragma unroll
    for (int r = 0; r < 16; ++r) v[r] = Z[swz(rb + 16*r)];
    dif16<-1,false>(v);
    make_tw(-TWO_PI_F * (float)m / 256.f, w);
    #pragma unroll
    for (int kk = 1; kk < 16; ++kk) v[REV4[kk]] = cmulf(v[REV4[kk]], w[kk]);
    #pragma unroll
    for (int kk = 0; kk < 16; ++kk) Z[swz(rb + 16*kk)] = v[REV4[kk]];
    __syncthreads();

    const int b3 = t << 4;
    #pragma unroll
    for (int r = 0; r < 16; ++r) v[r] = Z[swz(b3 + r)];
    dif16<-1,false>(v);
    #pragma unroll
    for (int kk = 0; kk < 16; ++kk) Z[swz(b3 + kk)] = v[REV4[kk]];
}

// digit-reversed (base-16) position of bin j, swizzled
__device__ __forceinline__ int binpos(int j) {
    return swz( ((j&15)<<8) | (((j>>4)&15)<<4) | (j>>8) );
}

// e^{-i pi/16}: step between combine bins j = t+256s as s increments
#define WSTEP_RE 0.980785280403230449f
#define WSTEP_IM -0.195090322016128268f

__global__ __launch_bounds__(THREADS, 4)
void fftconv_fused(const float* __restrict__ x, const float* __restrict__ k,
                   float* __restrict__ out) {
    __shared__ float2 Z[NFFT];
    constexpr int REV4[16] = {0,8,4,12,2,10,6,14,1,9,5,13,3,11,7,15};

    const int t  = threadIdx.x;
    const int hh = blockIdx.x;

    // ---- forward FFT of the k row (once per h) ----
    const float2* kp = (const float2*)(k + (size_t)hh * L_DIM);
    fwd_fft_row(kp, Z, t);
    __syncthreads();

    // ---- extract this thread's K-spectrum values into registers ----
    float2 kfj[8], kfm[8], kf2;
    {
        float sn, cs; __sincosf(-PI_F * (float)t / (float)NFFT, &sn, &cs);
        float2 wj = make_float2(cs, sn);              // e^{-i pi j/4096}, j=t
        const float2 WS = make_float2(WSTEP_RE, WSTEP_IM);
        kf2 = Z[swz(8)];                              // packed Z_k[2048], drev(2048)=8
        #pragma unroll
        for (int s = 0; s < 8; ++s) {
            int j = t + 256*s;
            if (j == 0) {
                float2 zk = Z[0];
                kfj[0] = make_float2(zk.x + zk.y, zk.x - zk.y);  // (A[0], A[4096]) both real
                kfm[0] = make_float2(0.f, 0.f);
            } else {
                int jm = NFFT - j;
                float2 zkj = Z[binpos(j)], zkm = Z[binpos(jm)];
                float2 Ke = make_float2(0.5f*(zkj.x + zkm.x), 0.5f*(zkj.y - zkm.y));
                float2 dk = make_float2(zkj.x - zkm.x, zkj.y + zkm.y);
                float2 Ko = make_float2(0.5f*dk.y, -0.5f*dk.x);
                float2 tk = cmulf(wj, Ko);
                kfj[s] = caddf(Ke, tk);                           // A_k[j]
                kfm[s] = make_float2(Ke.x - tk.x, -(Ke.y - tk.y)); // A_k[4096-j]
            }
            wj = cmulf(wj, WS);
        }
    }
    __syncthreads();   // all reads of Z (k spectrum) done before x overwrites it

    const int k1 = t >> 4, m = t & 15;
    const int rb = 256*k1 + m;
    const int b3 = t << 4;

    for (int b = 0; b < B_DIM; ++b) {
        const float2* xp = (const float2*)(x + ((size_t)(b*H_DIM + hh)) * L_DIM);
        fwd_fft_row(xp, Z, t);
        __syncthreads();

        // ---- combine: unpack x half-complex bins, multiply by reg K, repack ----
        {
            float sn, cs; __sincosf(-PI_F * (float)t / (float)NFFT, &sn, &cs);
            float2 wj = make_float2(cs, sn);
            const float2 WS = make_float2(WSTEP_RE, WSTEP_IM);
            #pragma unroll
            for (int s = 0; s < 8; ++s) {
                int j = t + 256*s;
                if (j == 0) {
                    float2 zx = Z[0];
                    float ax0 = zx.x + zx.y, axM = zx.x - zx.y;
                    float y0 = ax0 * kfj[0].x, yM = axM * kfj[0].y;
                    Z[0] = make_float2(0.5f*(y0 + yM), 0.5f*(y0 - yM));
                    int p2 = swz(8);
                    Z[p2] = cmulf(Z[p2], kf2);        // self-paired bin 2048
                } else {
                    int jm = NFFT - j;
                    int pj = binpos(j), pm = binpos(jm);
                    float2 zxj = Z[pj], zxm = Z[pm];

                    float2 Xe = make_float2(0.5f*(zxj.x + zxm.x), 0.5f*(zxj.y - zxm.y));
                    float2 dx = make_float2(zxj.x - zxm.x, zxj.y + zxm.y);
                    float2 Xo = make_float2(0.5f*dx.y, -0.5f*dx.x);
                    float2 tx = cmulf(wj, Xo);
                    float2 Axj = caddf(Xe, tx);
                    float2 Axm = make_float2(Xe.x - tx.x, -(Xe.y - tx.y));

                    float2 Yj = cmulf(Axj, kfj[s]);
                    float2 Ym = cmulf(Axm, kfm[s]);

                    float2 u  = make_float2(0.5f*(Yj.x + Ym.x), 0.5f*(Yj.y - Ym.y));
                    float2 dd = make_float2(Yj.x - Ym.x, Yj.y + Ym.y);
                    float2 wc = make_float2(wj.x, -wj.y);
                    float2 vv = cmulf(wc, dd);
                    vv.x *= 0.5f; vv.y *= 0.5f;
                    Z[pj] = make_float2(u.x - vv.y, u.y + vv.x);
                    Z[pm] = make_float2(u.x + vv.y, -(u.y - vv.x));
                }
                wj = cmulf(wj, WS);
            }
        }
        __syncthreads();

        float2 vx[16], w[16];

        // ---- inverse level A: contiguous 16-blocks, pure iDFT ----
        #pragma unroll
        for (int r = 0; r < 16; ++r) vx[REV4[r]] = Z[swz(b3 + r)];
        dit16<1,false>(vx);
        #pragma unroll
        for (int mm = 0; mm < 16; ++mm) Z[swz(b3 + mm)] = vx[mm];
        __syncthreads();

        // ---- inverse level B: untwiddle then iDFT over stride-16 ----
        make_tw(TWO_PI_F * (float)m / 256.f, w);
        #pragma unroll
        for (int kk = 0; kk < 16; ++kk) {
            float2 val = Z[swz(rb + 16*kk)];
            if (kk > 0) val = cmulf(val, w[kk]);
            vx[REV4[kk]] = val;
        }
        dit16<1,false>(vx);
        #pragma unroll
        for (int r = 0; r < 16; ++r) Z[swz(rb + 16*r)] = vx[r];
        __syncthreads();

        // ---- inverse level C: untwiddle, half iDFT (only first 8 outputs), store ----
        make_tw(TWO_PI_F * (float)t / (float)NFFT, w);
        #pragma unroll
        for (int kk = 0; kk < 16; ++kk) {
            float2 val = Z[swz(256*kk + t)];
            if (kk > 0) val = cmulf(val, w[kk]);
            vx[REV4[kk]] = val;
        }
        dit16<1,true>(vx);
        float2* op = (float2*)(out + ((size_t)(b*H_DIM + hh)) * L_DIM);
        const float sc = 1.f / (float)NFFT;
        #pragma unroll
        for (int n1 = 0; n1 < 8; ++n1) {
            float2 z = vx[n1];
            op[256*n1 + t] = make_float2(z.x*sc, z.y*sc);
        }
        __syncthreads();   // invC reads of Z done before next b's fwd writes
    }
}

extern "C" void kernel_launch(void* const* d_in, const int* in_sizes, int n_in,
                              void* d_out, int out_size, void* d_ws, size_t ws_size,
                              hipStream_t stream) {
    const float* x = (const float*)d_in[0];
    const float* k = (const float*)d_in[1];
    float* out = (float*)d_out;
    fftconv_fused<<<dim3(H_DIM), dim3(THREADS), 0, stream>>>(x, k, out);
}

// Round 5
// 630.995 us; speedup vs baseline: 1.0340x; 1.0340x over previous
//
#include <hip/hip_runtime.h>

#define THREADS 256
#define B_DIM   4
#define H_DIM   1024
#define L_DIM   4096
#define NFFT    4096      // half-length complex FFT size (real n = 8192)
#define PI_F     3.14159265358979323846f
#define TWO_PI_F 6.28318530717958647692f

__device__ __forceinline__ float2 cmulf(float2 a, float2 b) {
    return make_float2(a.x*b.x - a.y*b.y, a.x*b.y + a.y*b.x);
}
__device__ __forceinline__ float2 caddf(float2 a, float2 b){ return make_float2(a.x+b.x, a.y+b.y); }
__device__ __forceinline__ float2 csubf(float2 a, float2 b){ return make_float2(a.x-b.x, a.y-b.y); }

// XOR swizzle: bank-pair = d2^d1^d0 -> ~4 lanes/bank-pair (b64 floor) on all patterns
__device__ __forceinline__ int swz(int i) { return i ^ ((i>>4)&15) ^ ((i>>8)&15); }

// w[kk] = e^{i*base*kk}, kk=1..15, via 1 sincos + squaring tree (14 cmul)
__device__ __forceinline__ void make_tw(float base, float2 w[16]) {
    float sn, cs; __sincosf(base, &sn, &cs);
    w[1]  = make_float2(cs, sn);
    w[2]  = cmulf(w[1], w[1]);
    w[3]  = cmulf(w[2], w[1]);
    w[4]  = cmulf(w[2], w[2]);
    w[5]  = cmulf(w[4], w[1]);
    w[6]  = cmulf(w[4], w[2]);
    w[7]  = cmulf(w[4], w[3]);
    w[8]  = cmulf(w[4], w[4]);
    w[9]  = cmulf(w[8], w[1]);
    w[10] = cmulf(w[8], w[2]);
    w[11] = cmulf(w[8], w[3]);
    w[12] = cmulf(w[8], w[4]);
    w[13] = cmulf(w[8], w[5]);
    w[14] = cmulf(w[8], w[6]);
    w[15] = cmulf(w[8], w[7]);
}

// W16^q = e^{SGN*2pi*i*q/16}
__device__ __forceinline__ float2 w16c(int q, float s) {
    constexpr float C[8] = {1.f, 0.9238795325f, 0.7071067812f, 0.3826834324f,
                            0.f, -0.3826834324f, -0.7071067812f, -0.9238795325f};
    constexpr float S[8] = {0.f, 0.3826834324f, 0.7071067812f, 0.9238795325f,
                            1.f, 0.9238795325f, 0.7071067812f, 0.3826834324f};
    return make_float2(C[q], s*S[q]);
}

template<int SGN>
__device__ __forceinline__ float2 twq(float2 d, int q) {
    if (q == 0) return d;
    if (q == 4) return make_float2((float)(-SGN)*d.y, (float)SGN*d.x);
    return cmulf(d, w16c(q, (float)SGN));
}

// Radix-2 DIF 16-pt DFT: natural-order input, bit-reversed output (bin k at reg REV4[k]).
template<int SGN, bool HZ>
__device__ __forceinline__ void dif16(float2 v[16]) {
    if (HZ) {
        #pragma unroll
        for (int i = 0; i < 8; ++i) {
            float2 a = v[i];
            v[i+8] = twq<SGN>(a, i);
        }
    } else {
        #pragma unroll
        for (int i = 0; i < 8; ++i) {
            float2 a = v[i], b = v[i+8];
            v[i]   = caddf(a,b);
            v[i+8] = twq<SGN>(csubf(a,b), i);
        }
    }
    #pragma unroll
    for (int h = 4; h >= 1; h >>= 1) {
        const int step = 8 / h;
        #pragma unroll
        for (int g = 0; g < 16; g += 2*h) {
            #pragma unroll
            for (int i = 0; i < h; ++i) {
                float2 a = v[g+i], b = v[g+i+h];
                v[g+i]   = caddf(a,b);
                v[g+i+h] = twq<SGN>(csubf(a,b), i*step);
            }
        }
    }
}

// Radix-2 DIT 16-pt DFT: bit-reversed input, natural-order output.
// HALF: only outputs v[0..7] are needed (skip the subs of the final stage).
template<int SGN, bool HALF>
__device__ __forceinline__ void dit16(float2 v[16]) {
    #pragma unroll
    for (int h = 1; h <= 4; h <<= 1) {
        const int step = 8 / h;
        #pragma unroll
        for (int g = 0; g < 16; g += 2*h) {
            #pragma unroll
            for (int i = 0; i < h; ++i) {
                float2 a = v[g+i];
                float2 b = twq<SGN>(v[g+i+h], i*step);
                v[g+i]   = caddf(a,b);
                v[g+i+h] = csubf(a,b);
            }
        }
    }
    // final stage h=8
    #pragma unroll
    for (int i = 0; i < 8; ++i) {
        float2 a = v[i];
        float2 b = twq<SGN>(v[i+8], i);
        v[i] = caddf(a,b);
        if (!HALF) v[i+8] = csubf(a,b);
    }
}

// Forward 3-level radix-16 FFT of a zero-padded packed real row into LDS Z.
// On exit (no trailing barrier): position p holds bin drev(p), swizzled.
__device__ __forceinline__ void fwd_fft_row(const float2* __restrict__ src, float2* Z, int t) {
    constexpr int REV4[16] = {0,8,4,12,2,10,6,14,1,9,5,13,3,11,7,15};
    float2 v[16], w[16];
    #pragma unroll
    for (int r = 0; r < 8; ++r) v[r] = src[256*r + t];
    dif16<-1, true>(v);
    make_tw(-TWO_PI_F * (float)t / (float)NFFT, w);
    #pragma unroll
    for (int kk = 1; kk < 16; ++kk) v[REV4[kk]] = cmulf(v[REV4[kk]], w[kk]);
    #pragma unroll
    for (int kk = 0; kk < 16; ++kk) Z[swz(256*kk + t)] = v[REV4[kk]];
    __syncthreads();

    const int k1 = t >> 4, m = t & 15;
    const int rb = 256*k1 + m;
    #pragma unroll
    for (int r = 0; r < 16; ++r) v[r] = Z[swz(rb + 16*r)];
    dif16<-1,false>(v);
    make_tw(-TWO_PI_F * (float)m / 256.f, w);
    #pragma unroll
    for (int kk = 1; kk < 16; ++kk) v[REV4[kk]] = cmulf(v[REV4[kk]], w[kk]);
    #pragma unroll
    for (int kk = 0; kk < 16; ++kk) Z[swz(rb + 16*kk)] = v[REV4[kk]];
    __syncthreads();

    const int b3 = t << 4;
    #pragma unroll
    for (int r = 0; r < 16; ++r) v[r] = Z[swz(b3 + r)];
    dif16<-1,false>(v);
    #pragma unroll
    for (int kk = 0; kk < 16; ++kk) Z[swz(b3 + kk)] = v[REV4[kk]];
}

// digit-reversed (base-16) position of bin j, swizzled
__device__ __forceinline__ int binpos(int j) {
    return swz( ((j&15)<<8) | (((j>>4)&15)<<4) | (j>>8) );
}

// e^{-i pi/16}: step between combine bins j = t+256s as s increments
#define WSTEP_RE 0.980785280403230449f
#define WSTEP_IM -0.195090322016128268f

// Exact 4 waves/EU: 128-VGPR budget, no heuristic push to 8 waves (which caused
// the R4 scratch-spill catastrophe: VGPR_Count=64 + 1.3 GB spill traffic).
__global__ __attribute__((amdgpu_flat_work_group_size(256, 256)))
           __attribute__((amdgpu_waves_per_eu(4, 4)))
void fftconv_fused(const float* __restrict__ x, const float* __restrict__ k,
                   float* __restrict__ out) {
    __shared__ float2 Z[NFFT];
    constexpr int REV4[16] = {0,8,4,12,2,10,6,14,1,9,5,13,3,11,7,15};

    const int t  = threadIdx.x;
    const int hh = blockIdx.x;

    // ---- forward FFT of the k row (once per h) ----
    const float2* kp = (const float2*)(k + (size_t)hh * L_DIM);
    fwd_fft_row(kp, Z, t);
    __syncthreads();

    // ---- extract this thread's K-spectrum values into registers ----
    float2 kfj[8], kfm[8], kf2;
    {
        float sn, cs; __sincosf(-PI_F * (float)t / (float)NFFT, &sn, &cs);
        float2 wj = make_float2(cs, sn);              // e^{-i pi j/4096}, j=t
        const float2 WS = make_float2(WSTEP_RE, WSTEP_IM);
        kf2 = Z[swz(8)];                              // packed Z_k[2048], drev(2048)=8
        #pragma unroll
        for (int s = 0; s < 8; ++s) {
            int j = t + 256*s;
            if (j == 0) {
                float2 zk = Z[0];
                kfj[0] = make_float2(zk.x + zk.y, zk.x - zk.y);  // (A[0], A[4096]) both real
                kfm[0] = make_float2(0.f, 0.f);
            } else {
                int jm = NFFT - j;
                float2 zkj = Z[binpos(j)], zkm = Z[binpos(jm)];
                float2 Ke = make_float2(0.5f*(zkj.x + zkm.x), 0.5f*(zkj.y - zkm.y));
                float2 dk = make_float2(zkj.x - zkm.x, zkj.y + zkm.y);
                float2 Ko = make_float2(0.5f*dk.y, -0.5f*dk.x);
                float2 tk = cmulf(wj, Ko);
                kfj[s] = caddf(Ke, tk);                           // A_k[j]
                kfm[s] = make_float2(Ke.x - tk.x, -(Ke.y - tk.y)); // A_k[4096-j]
            }
            wj = cmulf(wj, WS);
        }
    }
    __syncthreads();   // all reads of Z (k spectrum) done before x overwrites it

    const int k1 = t >> 4, m = t & 15;
    const int rb = 256*k1 + m;
    const int b3 = t << 4;

    for (int b = 0; b < B_DIM; ++b) {
        const float2* xp = (const float2*)(x + ((size_t)(b*H_DIM + hh)) * L_DIM);
        fwd_fft_row(xp, Z, t);
        __syncthreads();

        // ---- combine: unpack x half-complex bins, multiply by reg K, repack ----
        {
            float sn, cs; __sincosf(-PI_F * (float)t / (float)NFFT, &sn, &cs);
            float2 wj = make_float2(cs, sn);
            const float2 WS = make_float2(WSTEP_RE, WSTEP_IM);
            #pragma unroll
            for (int s = 0; s < 8; ++s) {
                int j = t + 256*s;
                if (j == 0) {
                    float2 zx = Z[0];
                    float ax0 = zx.x + zx.y, axM = zx.x - zx.y;
                    float y0 = ax0 * kfj[0].x, yM = axM * kfj[0].y;
                    Z[0] = make_float2(0.5f*(y0 + yM), 0.5f*(y0 - yM));
                    int p2 = swz(8);
                    Z[p2] = cmulf(Z[p2], kf2);        // self-paired bin 2048
                } else {
                    int jm = NFFT - j;
                    int pj = binpos(j), pm = binpos(jm);
                    float2 zxj = Z[pj], zxm = Z[pm];

                    float2 Xe = make_float2(0.5f*(zxj.x + zxm.x), 0.5f*(zxj.y - zxm.y));
                    float2 dx = make_float2(zxj.x - zxm.x, zxj.y + zxm.y);
                    float2 Xo = make_float2(0.5f*dx.y, -0.5f*dx.x);
                    float2 tx = cmulf(wj, Xo);
                    float2 Axj = caddf(Xe, tx);
                    float2 Axm = make_float2(Xe.x - tx.x, -(Xe.y - tx.y));

                    float2 Yj = cmulf(Axj, kfj[s]);
                    float2 Ym = cmulf(Axm, kfm[s]);

                    float2 u  = make_float2(0.5f*(Yj.x + Ym.x), 0.5f*(Yj.y - Ym.y));
                    float2 dd = make_float2(Yj.x - Ym.x, Yj.y + Ym.y);
                    float2 wc = make_float2(wj.x, -wj.y);
                    float2 vv = cmulf(wc, dd);
                    vv.x *= 0.5f; vv.y *= 0.5f;
                    Z[pj] = make_float2(u.x - vv.y, u.y + vv.x);
                    Z[pm] = make_float2(u.x + vv.y, -(u.y - vv.x));
                }
                wj = cmulf(wj, WS);
            }
        }
        __syncthreads();

        float2 vx[16], w[16];

        // ---- inverse level A: contiguous 16-blocks, pure iDFT ----
        #pragma unroll
        for (int r = 0; r < 16; ++r) vx[REV4[r]] = Z[swz(b3 + r)];
        dit16<1,false>(vx);
        #pragma unroll
        for (int mm = 0; mm < 16; ++mm) Z[swz(b3 + mm)] = vx[mm];
        __syncthreads();

        // ---- inverse level B: untwiddle then iDFT over stride-16 ----
        make_tw(TWO_PI_F * (float)m / 256.f, w);
        #pragma unroll
        for (int kk = 0; kk < 16; ++kk) {
            float2 val = Z[swz(rb + 16*kk)];
            if (kk > 0) val = cmulf(val, w[kk]);
            vx[REV4[kk]] = val;
        }
        dit16<1,false>(vx);
        #pragma unroll
        for (int r = 0; r < 16; ++r) Z[swz(rb + 16*r)] = vx[r];
        __syncthreads();

        // ---- inverse level C: untwiddle, half iDFT (only first 8 outputs), store ----
        make_tw(TWO_PI_F * (float)t / (float)NFFT, w);
        #pragma unroll
        for (int kk = 0; kk < 16; ++kk) {
            float2 val = Z[swz(256*kk + t)];
            if (kk > 0) val = cmulf(val, w[kk]);
            vx[REV4[kk]] = val;
        }
        dit16<1,true>(vx);
        float2* op = (float2*)(out + ((size_t)(b*H_DIM + hh)) * L_DIM);
        const float sc = 1.f / (float)NFFT;
        #pragma unroll
        for (int n1 = 0; n1 < 8; ++n1) {
            float2 z = vx[n1];
            op[256*n1 + t] = make_float2(z.x*sc, z.y*sc);
        }
        __syncthreads();   // invC reads of Z done before next b's fwd writes
    }
}

extern "C" void kernel_launch(void* const* d_in, const int* in_sizes, int n_in,
                              void* d_out, int out_size, void* d_ws, size_t ws_size,
                              hipStream_t stream) {
    const float* x = (const float*)d_in[0];
    const float* k = (const float*)d_in[1];
    float* out = (float*)d_out;
    fftconv_fused<<<dim3(H_DIM), dim3(THREADS), 0, stream>>>(x, k, out);
}